// Round 1
// baseline (723.735 us; speedup 1.0000x reference)
//
#include <hip/hip_runtime.h>

#define DIM 128
#define SAMP 2048
#define KNEG 128
#define GAMMA 12.0f

// One block per (sample, part). 256 threads = 4 waves.
// Phase 1: stage hr = h + r and rt = r - t in LDS; compute pos score.
// Phase 2: each 32-lane half-wave gathers one 512B embedding row per iter
//          (float4/lane), L1-distance vs hr (tail-corrupt) or rt (head-corrupt),
//          reduce over 32 lanes with shfl, lane 0 writes the score.
__global__ __launch_bounds__(256) void transe_score_kernel(
    const float* __restrict__ emb,     // [N, D]
    const float* __restrict__ relG2,   // [R2, D]
    const float* __restrict__ relG1,   // [R1, D]
    const float* __restrict__ relTO,   // [D]
    const int* __restrict__ head1, const int* __restrict__ rel1,
    const int* __restrict__ tail1, const int* __restrict__ nt1,
    const int* __restrict__ nh1,
    const int* __restrict__ head2, const int* __restrict__ rel2,
    const int* __restrict__ tail2, const int* __restrict__ nt2,
    const int* __restrict__ nh2,
    const int* __restrict__ head3, const int* __restrict__ tail3,
    const int* __restrict__ nt3, const int* __restrict__ nh3,
    float* __restrict__ out)
{
    const int s    = blockIdx.x;     // sample
    const int part = blockIdx.y;     // 0,1,2
    const int tid  = threadIdx.x;    // 0..255
    const int lane = tid & 63;
    const int wid  = tid >> 6;       // wave id 0..3
    const int half = (lane >> 5);    // 0/1 within wave
    const int l32  = lane & 31;      // lane within half-wave

    __shared__ __align__(16) float hr[DIM];      // h + r
    __shared__ __align__(16) float rt[DIM];      // r - t
    __shared__ float posbuf[DIM];

    // part-specific pointers (block-uniform branch)
    const int* hidx; const int* tidx; const int* ntidx; const int* nhidx;
    const float* rrow;
    if (part == 0)      { hidx=head1; tidx=tail1; ntidx=nt1; nhidx=nh1; rrow = relG2 + (long)rel1[s]*DIM; }
    else if (part == 1) { hidx=head2; tidx=tail2; ntidx=nt2; nhidx=nh2; rrow = relG1 + (long)rel2[s]*DIM; }
    else                { hidx=head3; tidx=tail3; ntidx=nt3; nhidx=nh3; rrow = relTO; }

    const int h = hidx[s];
    const int t = tidx[s];

    if (tid < DIM) {
        float hv = emb[(long)h*DIM + tid];
        float rv = rrow[tid];
        float tv = emb[(long)t*DIM + tid];
        float a  = hv + rv;
        hr[tid] = a;
        rt[tid] = rv - tv;
        posbuf[tid] = fabsf(a - tv);
    }
    __syncthreads();

    // Output layout: per part P = S + 2*S*K; [pos | neg_tail | neg_head]
    const long P       = (long)SAMP + 2L*SAMP*KNEG;
    const long pos_off = (long)part * P;
    const long nt_off  = pos_off + SAMP;
    const long nh_off  = nt_off + (long)SAMP*KNEG;

    // pos score: wave 0 reduces posbuf[128]
    if (wid == 0) {
        float v = posbuf[lane] + posbuf[lane + 64];
        #pragma unroll
        for (int off = 32; off; off >>= 1) v += __shfl_down(v, off, 64);
        if (lane == 0) out[pos_off + s] = GAMMA - v;
    }

    // per-lane register copy of the 4 relevant hr/rt elements
    const float4 hrv = ((const float4*)hr)[l32];
    const float4 rtv = ((const float4*)rt)[l32];

    // 256 rows (128 neg_tail then 128 neg_head), 8 rows/iteration
    #pragma unroll 4
    for (int iter = 0; iter < 32; ++iter) {
        const int r = iter * 8 + wid * 2 + half;     // row id 0..255
        const bool isTail = (r < KNEG);              // uniform per wave (8-row granularity)
        const int j = isTail ? r : r - KNEG;
        const int idx = isTail ? ntidx[s*KNEG + j] : nhidx[s*KNEG + j];
        const float4 e = ((const float4*)(emb + (long)idx * DIM))[l32];

        float sum;
        if (isTail) {
            sum = fabsf(hrv.x - e.x) + fabsf(hrv.y - e.y)
                + fabsf(hrv.z - e.z) + fabsf(hrv.w - e.w);
        } else {
            sum = fabsf(e.x + rtv.x) + fabsf(e.y + rtv.y)
                + fabsf(e.z + rtv.z) + fabsf(e.w + rtv.w);
        }
        #pragma unroll
        for (int off = 16; off; off >>= 1) sum += __shfl_down(sum, off, 32);
        if (l32 == 0) {
            const long o = isTail ? (nt_off + (long)s*KNEG + j)
                                  : (nh_off + (long)s*KNEG + j);
            out[o] = GAMMA - sum;
        }
    }
}

extern "C" void kernel_launch(void* const* d_in, const int* in_sizes, int n_in,
                              void* d_out, int out_size, void* d_ws, size_t ws_size,
                              hipStream_t stream) {
    const float* emb   = (const float*)d_in[0];
    const float* relG2 = (const float*)d_in[1];
    const float* relG1 = (const float*)d_in[2];
    const float* relTO = (const float*)d_in[3];
    const int* head1 = (const int*)d_in[4];
    const int* rel1  = (const int*)d_in[5];
    const int* tail1 = (const int*)d_in[6];
    const int* nt1   = (const int*)d_in[7];
    const int* nh1   = (const int*)d_in[8];
    const int* head2 = (const int*)d_in[9];
    const int* rel2  = (const int*)d_in[10];
    const int* tail2 = (const int*)d_in[11];
    const int* nt2   = (const int*)d_in[12];
    const int* nh2   = (const int*)d_in[13];
    const int* head3 = (const int*)d_in[14];
    const int* tail3 = (const int*)d_in[15];
    const int* nt3   = (const int*)d_in[16];
    const int* nh3   = (const int*)d_in[17];
    float* out = (float*)d_out;

    dim3 grid(SAMP, 3);
    dim3 block(256);
    transe_score_kernel<<<grid, block, 0, stream>>>(
        emb, relG2, relG1, relTO,
        head1, rel1, tail1, nt1, nh1,
        head2, rel2, tail2, nt2, nh2,
        head3, tail3, nt3, nh3,
        out);
}

// Round 2
// 697.533 us; speedup vs baseline: 1.0376x; 1.0376x over previous
//
#include <hip/hip_runtime.h>

#define DIM 128
#define SAMP 2048
#define KNEG 128
#define GAMMA 12.0f

// One block per (sample, part). 256 threads = 4 waves.
// Phase 1: stage neg indices (256 ints) + hr = h+r, rt = r-t in LDS; pos score.
// Phase 2: two branch-free fully-unrolled loops (tail-corrupt, head-corrupt).
//          Each 32-lane half-wave gathers one 512B row (float4/lane), L1
//          distance, 5-step shfl reduce, score -> LDS.
// Phase 3: two coalesced 128-float output stores.
__global__ __launch_bounds__(256, 8) void transe_score_kernel(
    const float* __restrict__ emb,     // [N, D]
    const float* __restrict__ relG2,   // [R2, D]
    const float* __restrict__ relG1,   // [R1, D]
    const float* __restrict__ relTO,   // [D]
    const int* __restrict__ head1, const int* __restrict__ rel1,
    const int* __restrict__ tail1, const int* __restrict__ nt1,
    const int* __restrict__ nh1,
    const int* __restrict__ head2, const int* __restrict__ rel2,
    const int* __restrict__ tail2, const int* __restrict__ nt2,
    const int* __restrict__ nh2,
    const int* __restrict__ head3, const int* __restrict__ tail3,
    const int* __restrict__ nt3, const int* __restrict__ nh3,
    float* __restrict__ out)
{
    const int s    = blockIdx.x;     // sample
    const int part = blockIdx.y;     // 0,1,2
    const int tid  = threadIdx.x;    // 0..255
    const int lane = tid & 63;
    const int wid  = tid >> 6;       // wave id 0..3
    const int half = (lane >> 5);    // 0/1 within wave
    const int l32  = lane & 31;      // lane within half-wave
    const int c    = wid * 2 + half; // half-wave id 0..7

    __shared__ __align__(16) float hr[DIM];      // h + r
    __shared__ __align__(16) float rt[DIM];      // r - t
    __shared__ float posbuf[DIM];
    __shared__ int   idxbuf[2 * KNEG];           // [tail idxs | head idxs]
    __shared__ float scorebuf[2 * KNEG];         // [tail scores | head scores]

    // part-specific pointers (block-uniform branch)
    const int* hidx; const int* tidx; const int* ntidx; const int* nhidx;
    const float* rrow;
    if (part == 0)      { hidx=head1; tidx=tail1; ntidx=nt1; nhidx=nh1; rrow = relG2 + (long)rel1[s]*DIM; }
    else if (part == 1) { hidx=head2; tidx=tail2; ntidx=nt2; nhidx=nh2; rrow = relG1 + (long)rel2[s]*DIM; }
    else                { hidx=head3; tidx=tail3; ntidx=nt3; nhidx=nh3; rrow = relTO; }

    const int sK = s * KNEG;

    if (tid < DIM) {
        // stage tail-corrupt indices + compute hr/rt/posbuf
        idxbuf[tid] = ntidx[sK + tid];
        const int h = hidx[s];
        const int t = tidx[s];
        float hv = emb[(long)h*DIM + tid];
        float rv = rrow[tid];
        float tv = emb[(long)t*DIM + tid];
        float a  = hv + rv;
        hr[tid] = a;
        rt[tid] = rv - tv;
        posbuf[tid] = fabsf(a - tv);
    } else {
        // stage head-corrupt indices
        idxbuf[tid] = nhidx[sK + tid - KNEG];
    }
    __syncthreads();

    // Output layout: per part P = S + 2*S*K; [pos | neg_tail | neg_head]
    const long P       = (long)SAMP + 2L*SAMP*KNEG;
    const long pos_off = (long)part * P;
    const long nt_off  = pos_off + SAMP;
    const long nh_off  = nt_off + (long)SAMP*KNEG;

    // pos score: wave 0 reduces posbuf[128]
    if (wid == 0) {
        float v = posbuf[lane] + posbuf[lane + 64];
        #pragma unroll
        for (int off = 32; off; off >>= 1) v += __shfl_down(v, off, 64);
        if (lane == 0) out[pos_off + s] = GAMMA - v;
    }

    // per-lane register copy of the 4 relevant hr/rt elements
    const float4 hrv = ((const float4*)hr)[l32];
    const float4 rtv = ((const float4*)rt)[l32];

    // tail-corrupted: rows j = it*8 + c, j in [0,128)
    #pragma unroll
    for (int it = 0; it < 16; ++it) {
        const int j = it * 8 + c;
        const int idx = idxbuf[j];
        const float4 e = ((const float4*)(emb + (long)idx * DIM))[l32];
        float sum = fabsf(hrv.x - e.x) + fabsf(hrv.y - e.y)
                  + fabsf(hrv.z - e.z) + fabsf(hrv.w - e.w);
        #pragma unroll
        for (int off = 16; off; off >>= 1) sum += __shfl_down(sum, off, 32);
        if (l32 == 0) scorebuf[j] = GAMMA - sum;
    }

    // head-corrupted: rows j = it*8 + c
    #pragma unroll
    for (int it = 0; it < 16; ++it) {
        const int j = it * 8 + c;
        const int idx = idxbuf[KNEG + j];
        const float4 e = ((const float4*)(emb + (long)idx * DIM))[l32];
        float sum = fabsf(e.x + rtv.x) + fabsf(e.y + rtv.y)
                  + fabsf(e.z + rtv.z) + fabsf(e.w + rtv.w);
        #pragma unroll
        for (int off = 16; off; off >>= 1) sum += __shfl_down(sum, off, 32);
        if (l32 == 0) scorebuf[KNEG + j] = GAMMA - sum;
    }
    __syncthreads();

    // Phase 3: coalesced output stores
    if (tid < KNEG) out[nt_off + sK + tid] = scorebuf[tid];
    else            out[nh_off + sK + tid - KNEG] = scorebuf[tid];
}

extern "C" void kernel_launch(void* const* d_in, const int* in_sizes, int n_in,
                              void* d_out, int out_size, void* d_ws, size_t ws_size,
                              hipStream_t stream) {
    const float* emb   = (const float*)d_in[0];
    const float* relG2 = (const float*)d_in[1];
    const float* relG1 = (const float*)d_in[2];
    const float* relTO = (const float*)d_in[3];
    const int* head1 = (const int*)d_in[4];
    const int* rel1  = (const int*)d_in[5];
    const int* tail1 = (const int*)d_in[6];
    const int* nt1   = (const int*)d_in[7];
    const int* nh1   = (const int*)d_in[8];
    const int* head2 = (const int*)d_in[9];
    const int* rel2  = (const int*)d_in[10];
    const int* tail2 = (const int*)d_in[11];
    const int* nt2   = (const int*)d_in[12];
    const int* nh2   = (const int*)d_in[13];
    const int* head3 = (const int*)d_in[14];
    const int* tail3 = (const int*)d_in[15];
    const int* nt3   = (const int*)d_in[16];
    const int* nh3   = (const int*)d_in[17];
    float* out = (float*)d_out;

    dim3 grid(SAMP, 3);
    dim3 block(256);
    transe_score_kernel<<<grid, block, 0, stream>>>(
        emb, relG2, relG1, relTO,
        head1, rel1, tail1, nt1, nh1,
        head2, rel2, tail2, nt2, nh2,
        head3, tail3, nt3, nh3,
        out);
}